// Round 4
// baseline (421.492 us; speedup 1.0000x reference)
//
#include <hip/hip_runtime.h>

// Problem constants
#define DIMC 192
#define HID  48          // DIM / RED
#define HW   65536       // 256*256
#define WIDTH 256
#define NPLANE 768       // B * DIM

// ---------------------------------------------------------------------------
// Kernel 1: strip partial sums. Grid 3072 = 768 planes x 4 strips of 64 rows;
// 256 threads; each thread sums 16 float4. No occupancy tail.
// pp[plane*4 + strip] = raw SUM over the strip (normalized in conv).
// ---------------------------------------------------------------------------
__global__ __launch_bounds__(256) void k_pool(const float* __restrict__ x,
                                              float* __restrict__ pp) {
    const int plane = blockIdx.x >> 2;          // 0..767
    const int strip = blockIdx.x & 3;           // 0..3 (64 rows each)
    const float4* p = (const float4*)(x + (size_t)plane * HW + strip * 64 * WIDTH);
    const int t = threadIdx.x;
    float s = 0.f;
#pragma unroll
    for (int k = 0; k < 16; ++k) {
        float4 v = p[k * 256 + t];
        s += (v.x + v.y) + (v.z + v.w);
    }
#pragma unroll
    for (int off = 32; off > 0; off >>= 1) s += __shfl_down(s, off, 64);
    __shared__ float wsum[4];
    const int wave = t >> 6, lane = t & 63;
    if (lane == 0) wsum[wave] = s;
    __syncthreads();
    if (t == 0) pp[blockIdx.x] = (wsum[0] + wsum[1]) + (wsum[2] + wsum[3]);
}

// ---------------------------------------------------------------------------
// Kernel 2: weight-gen prologue + 4-tap masked depthwise conv.
//   out[y][x] = w00*X[y-1][x-1] + w01*X[y-1][x] + w02*X[y-1][x+1]
//             + w10*X[y  ][x-1] + bias[c]
//
// Dependency-free inner pipeline:
//   * 9 aligned float4 row-loads + 17 scalar halo loads are issued FIRST,
//     then the weight prologue runs (its VALU + barriers hide the latency).
//   * Column halos come from scalar global loads (L1/L2 hits — same lines as
//     neighbor lanes) instead of ds_bpermute shuffles: no lgkmcnt chains, no
//     per-row load->shuffle->compute serialization.
// Grid: 768 planes * 8 row-tiles = 6144 blocks; 4 waves x 8 rows each.
// ---------------------------------------------------------------------------
__global__ __launch_bounds__(256) void k_conv(
    const float* __restrict__ x,
    const float* __restrict__ pp,       // [768*4] strip sums
    const float* __restrict__ w1,       // [48,192]
    const float* __restrict__ gamma,
    const float* __restrict__ beta,
    const float* __restrict__ rmean,
    const float* __restrict__ rvar,
    const float* __restrict__ w2,       // [1728,48]
    const float* __restrict__ b2,       // [1728]
    const float* __restrict__ bias,
    float* __restrict__ out)
{
    const int plane = blockIdx.x >> 3;          // 0..767 (= b*192 + c)
    const int b = plane / DIMC;
    const int c = plane - b * DIMC;
    const int tid = threadIdx.x;
    const int wave = tid >> 6;
    const int lane = tid & 63;
    const int y0 = ((blockIdx.x & 7) << 5) + (wave << 3);
    const int x0 = lane << 2;                   // first pixel of this lane's float4

    const float*  xs  = x + (size_t)plane * HW;
    const float4* xp4 = (const float4*)xs;

    // ---- issue all tile loads up front (latency hidden by prologue) ----
    float4 R[9];    // rows y0-1 .. y0+7, aligned float4 at x0
    float  LA[9];   // X[row][x0-1] for rows y0-1 .. y0+7
    float  RA[8];   // X[row][x0+4] for rows y0-1 .. y0+6
#pragma unroll
    for (int r = 0; r < 9; ++r) {
        const int y = y0 - 1 + r;
        if (y < 0) {                            // only r==0 when y0==0 (uniform)
            R[r] = make_float4(0.f, 0.f, 0.f, 0.f);
            LA[r] = 0.f;
            if (r < 8) RA[r] = 0.f;
        } else {
            R[r] = xp4[y * 64 + lane];
            LA[r] = (lane == 0)  ? 0.f : xs[y * WIDTH + x0 - 1];
            if (r < 8) RA[r] = (lane == 63) ? 0.f : xs[y * WIDTH + x0 + 4];
        }
    }

    // ---- weight-gen prologue (VALU work overlaps the in-flight loads) ----
    __shared__ float P[DIMC];
    __shared__ float T[HID];
    __shared__ float W4[4];
    if (tid < DIMC) {
        float4 v = ((const float4*)pp)[b * DIMC + tid];  // 4 strip sums
        P[tid] = ((v.x + v.y) + (v.z + v.w)) * (1.0f / 65536.0f);
    }
    __syncthreads();
    {
        const int g = tid >> 2, l = tid & 3;    // 48 groups of 4 lanes
        if (g < HID) {
            const float* wr = w1 + g * DIMC;
            float acc = 0.f;
#pragma unroll 8
            for (int d = l; d < DIMC; d += 4) acc += P[d] * wr[d];
            acc += __shfl_xor(acc, 1, 64);
            acc += __shfl_xor(acc, 2, 64);
            if (l == 0) {
                const float inv = rsqrtf(rvar[g] + 1e-5f);
                float v = gamma[g] * (acc - rmean[g]) * inv + beta[g];
                T[g] = v > 0.f ? v : 0.f;
            }
        }
        __syncthreads();
        if (tid < 4) {                          // 4 unmasked taps of channel c
            const int o = c * 9 + tid;
            const float* wr = w2 + o * HID;
            float acc = b2[o];
#pragma unroll
            for (int j = 0; j < HID; ++j) acc += T[j] * wr[j];
            W4[tid] = acc;
        }
        __syncthreads();
    }
    const float4 wt = make_float4(W4[0], W4[1], W4[2], W4[3]); // {w00,w01,w02,w10}
    const float bs = bias[c];

    // ---- pure-VALU compute + stores (all inputs in registers) ----
    float4* op = (float4*)(out + (size_t)plane * HW);
#pragma unroll
    for (int r = 0; r < 8; ++r) {
        // output row y = y0 + r: a = R[r] (row y-1), bb = R[r+1] (row y)
        float4 o;
        o.x = wt.x * LA[r]   + wt.y * R[r].x + wt.z * R[r].y + wt.w * LA[r+1]   + bs;
        o.y = wt.x * R[r].x  + wt.y * R[r].y + wt.z * R[r].z + wt.w * R[r+1].x  + bs;
        o.z = wt.x * R[r].y  + wt.y * R[r].z + wt.z * R[r].w + wt.w * R[r+1].y  + bs;
        o.w = wt.x * R[r].z  + wt.y * R[r].w + wt.z * RA[r]  + wt.w * R[r+1].z  + bs;
        op[(y0 + r) * 64 + lane] = o;
    }
}

// ---------------------------------------------------------------------------
extern "C" void kernel_launch(void* const* d_in, const int* in_sizes, int n_in,
                              void* d_out, int out_size, void* d_ws, size_t ws_size,
                              hipStream_t stream) {
    const float* x     = (const float*)d_in[0];
    const float* w1    = (const float*)d_in[1];
    const float* gamma = (const float*)d_in[2];
    const float* beta  = (const float*)d_in[3];
    const float* rmean = (const float*)d_in[4];
    const float* rvar  = (const float*)d_in[5];
    const float* w2    = (const float*)d_in[6];
    const float* b2    = (const float*)d_in[7];
    const float* bias  = (const float*)d_in[8];
    float* out = (float*)d_out;

    float* pp = (float*)d_ws;   // 768*4 strip partial sums

    k_pool<<<NPLANE * 4, 256, 0, stream>>>(x, pp);
    k_conv<<<NPLANE * 8, 256, 0, stream>>>(x, pp, w1, gamma, beta,
                                           rmean, rvar, w2, b2, bias, out);
}